// Round 15
// baseline (743.053 us; speedup 1.0000x reference)
//
#include <hip/hip_runtime.h>
#include <hip/hip_bf16.h>

// Problem constants (reference: T,H,I,E,K = 4096,1024,2048,32,4)
#define T_TOK 4096
#define H_DIM 1024
#define I_DIM 2048
#define N_EXP 32
#define TOPK  4
#define TKTOT (T_TOK * TOPK)      // 16384 expert-row slots
#define ROWS_MAX 24576            // 4096 shared rows + <=20480 padded expert rows
#define MAX_TILES 192             // 32 shared tiles + <=159 expert tiles
#define BM 128
#define BK 64
#define WMAT ((size_t)I_DIM * H_DIM)   // 2M elements per expert matrix

typedef _Float16 f16;
typedef __attribute__((ext_vector_type(4))) f16  f16x4;
typedef __attribute__((ext_vector_type(8))) f16  f16x8;
typedef __attribute__((ext_vector_type(4))) float f32x4;

// async global->LDS, 16B per lane; LDS dest is wave-uniform base + lane*16
__device__ __forceinline__ void glds16(const f16* g, f16* l) {
  __builtin_amdgcn_global_load_lds(
      (const __attribute__((address_space(1))) void*)g,
      (__attribute__((address_space(3))) void*)l, 16, 0, 0);
}
__device__ __forceinline__ void sfence() { __builtin_amdgcn_sched_barrier(0); }
// m97-style per-k-step barrier: tile ks resident (vmcnt0), LDS writes vis.
__device__ __forceinline__ void bar_vm0() {
  sfence();
  asm volatile("s_waitcnt vmcnt(0) lgkmcnt(0)" ::: "memory");
  sfence();
  __builtin_amdgcn_s_barrier();
  sfence();
}

// ---------------------------------------------------------------- prep ----
__global__ void prep_kernel(const float* __restrict__ x, f16* __restrict__ xb,
                            int* __restrict__ row_token,
                            int* __restrict__ counts) {
  int gid = blockIdx.x * blockDim.x + threadIdx.x;   // 0 .. T*H/4-1
  float4 v = *(const float4*)(x + (size_t)gid * 4);
  f16x4 hv = { (f16)v.x, (f16)v.y, (f16)v.z, (f16)v.w };
  *(f16x4*)(xb + (size_t)gid * 4) = hv;
  if (gid < ROWS_MAX) row_token[gid] = (gid < T_TOK) ? gid : 0;
  if (gid < N_EXP) counts[gid] = 0;
}

// ------------------------------------------------- transpose+convert ------
// dst[mat][c][r] (f16) = src[mat][r][c] (fp32). mat==32 reads ssrc (shared).
// R,C multiples of 64. One 64x64 tile per block.
__global__ __launch_bounds__(256) void tcvt_kernel(
    const float* __restrict__ src, const float* __restrict__ ssrc,
    f16* __restrict__ dst, int R, int C, int tilesC) {
  int per = (R >> 6) * tilesC;
  int mat = blockIdx.x / per, rem = blockIdx.x % per;
  int r0 = (rem / tilesC) << 6, c0 = (rem % tilesC) << 6;
  const float* s = (mat < N_EXP ? src + (size_t)mat * R * C : ssrc)
                   + (size_t)r0 * C + c0;
  f16* d = dst + (size_t)mat * R * C + (size_t)c0 * R + r0;

  __shared__ float t[64][65];
  int tid = threadIdx.x;
  int rr = tid >> 2, cc = (tid & 3) * 16;
#pragma unroll
  for (int j = 0; j < 4; ++j) {
    float4 v = *(const float4*)(s + (size_t)rr * C + cc + 4 * j);
    t[rr][cc + 4 * j + 0] = v.x; t[rr][cc + 4 * j + 1] = v.y;
    t[rr][cc + 4 * j + 2] = v.z; t[rr][cc + 4 * j + 3] = v.w;
  }
  __syncthreads();
  f16x8 o0, o1;
#pragma unroll
  for (int j = 0; j < 8; ++j) o0[j] = (f16)t[cc + j][rr];
#pragma unroll
  for (int j = 0; j < 8; ++j) o1[j] = (f16)t[cc + 8 + j][rr];
  *(f16x8*)(d + (size_t)rr * R + cc) = o0;
  *(f16x8*)(d + (size_t)rr * R + cc + 8) = o1;
}

// -------------------------------------------------------------- router ----
__global__ void router_kernel(const float* __restrict__ x,
                              const float* __restrict__ rw,
                              int* __restrict__ expert_sel,
                              float* __restrict__ weight_sel,
                              int* __restrict__ counts) {
  int wid = threadIdx.x >> 6, lane = threadIdx.x & 63;
  int t = blockIdx.x * 4 + wid;
  float xr[16];
#pragma unroll
  for (int j = 0; j < 16; ++j) xr[j] = x[(size_t)t * H_DIM + lane + j * 64];
  float l[32];
#pragma unroll
  for (int e = 0; e < 32; ++e) {
    float p = 0.f;
#pragma unroll
    for (int j = 0; j < 16; ++j) p += xr[j] * rw[(size_t)e * H_DIM + lane + j * 64];
#pragma unroll
    for (int off = 32; off; off >>= 1) p += __shfl_xor(p, off, 64);
    l[e] = p;
  }
  if (lane == 0) {
    unsigned used = 0;
    int sel[4]; float lv[4];
#pragma unroll
    for (int k = 0; k < 4; ++k) {
      float bv = -3.4e38f; int bi = 0;
#pragma unroll
      for (int e = 0; e < 32; ++e) {
        bool better = (((used >> e) & 1u) == 0u) && (l[e] > bv);
        bv = better ? l[e] : bv;
        bi = better ? e : bi;
      }
      used |= 1u << bi; sel[k] = bi; lv[k] = bv;
    }
    float m = lv[0];
    float p0 = __expf(lv[0] - m), p1 = __expf(lv[1] - m);
    float p2 = __expf(lv[2] - m), p3 = __expf(lv[3] - m);
    float s = p0 + p1 + p2 + p3;
    float wv[4] = { p0 / s, p1 / s, p2 / s, p3 / s };
#pragma unroll
    for (int k = 0; k < 4; ++k) {
      expert_sel[t * 4 + k] = sel[k];
      weight_sel[t * 4 + k] = wv[k];
      atomicAdd(&counts[sel[k]], 1);
    }
  }
}

// ---------------------------------------------------------------- scan ----
__global__ void scan_kernel(const int* __restrict__ counts, int* __restrict__ cursor,
                            int* __restrict__ tile_expert, int* __restrict__ tile_row0,
                            int* __restrict__ ntiles) {
  int lane = threadIdx.x;                      // 64 threads, one wave
  if (lane < T_TOK / BM) { tile_expert[lane] = N_EXP; tile_row0[lane] = lane * BM; }
  int nte = 0, rows = 0;
  if (lane < N_EXP) {
    int c = counts[lane];
    nte = (c + BM - 1) / BM;
    rows = nte * BM;
  }
  int pnte = nte, prows = rows;
#pragma unroll
  for (int off = 1; off < 64; off <<= 1) {
    int t1 = __shfl_up(pnte, off, 64);
    int t2 = __shfl_up(prows, off, 64);
    if (lane >= off) { pnte += t1; prows += t2; }
  }
  int excl_nte = pnte - nte, excl_rows = prows - rows;
  if (lane < N_EXP) {
    int pos = T_TOK + excl_rows;
    cursor[lane] = pos;
    int tb = T_TOK / BM + excl_nte;
    for (int i = 0; i < nte; ++i) {
      tile_expert[tb + i] = lane;
      tile_row0[tb + i] = pos + i * BM;
    }
    if (lane == N_EXP - 1) ntiles[0] = tb + nte;
  }
}

// ------------------------------------------------------------- scatter ----
__global__ void scatter_kernel(const int* __restrict__ expert_sel,
                               int* __restrict__ cursor,
                               int* __restrict__ row_token,
                               int* __restrict__ slot_of) {
  int i = blockIdx.x * blockDim.x + threadIdx.x;
  if (i >= TKTOT) return;
  int e = expert_sel[i];
  int pos = atomicAdd(&cursor[e], 1);
  row_token[pos] = i >> 2;
  slot_of[i] = pos;
}

// ---------------------------------------------------------------- GEMM1 ---
// m97-X structure: per k-step = bar(vmcnt0) -> issue 8 glds16 (A4,Bg2,Bu2,
// next tile, other buffer) -> 32 MFMA/wave. All staging via global_load_lds
// (f16 transposed weights); no B registers, no in-loop cvt, ONE barrier.
__global__ __launch_bounds__(256, 2) void gemm1_kernel(
    const f16* __restrict__ xb,
    const f16* __restrict__ gT, const f16* __restrict__ uT,
    const int* __restrict__ row_token,
    const int* __restrict__ tile_expert, const int* __restrict__ tile_row0,
    const int* __restrict__ ntiles, f16* __restrict__ hbuf) {
  // XCD-aware swizzle: grid 192*32 = 6144 = 8*768 consecutive per XCD
  int d = blockIdx.y * gridDim.x + blockIdx.x;
  int l = (d & 7) * 768 + (d >> 3);
  int bx = l % MAX_TILES;
  int n0 = (l / MAX_TILES) * 64;
  if (bx >= ntiles[0]) return;
  int e = tile_expert[bx];       // 0..31 expert, 32 = shared (gT/uT slot 32)
  int row0 = tile_row0[bx];
  const f16* wg = gT + (size_t)e * WMAT;
  const f16* wu = uT + (size_t)e * WMAT;

  // LDS per buf: A 128*64 + Bg 64*64 + Bu 64*64 = 16384 f16; dbuf = 64 KB
  __shared__ __align__(16) f16 smem[2 * 16384];
  f16 (*Ct)[72] = (f16(*)[72])smem;   // epilogue reuse (9216 f16)

  int tid = threadIdx.x;
  int lane = tid & 63, wid = tid >> 6;
  int wm = wid >> 1, wn = wid & 1;
  int lr = lane & 15, lk = (lane >> 4) * 8;

  // A: 4 glds rounds; source k-chunk pre-swizzled on local row (m173)
  const f16* abase[4];
#pragma unroll
  for (int it = 0; it < 4; ++it) {
    int idx = tid + it * 256;
    int arow = idx >> 3, sl = idx & 7;
    abase[it] = xb + (size_t)row_token[row0 + arow] * H_DIM + ((sl ^ (arow & 7)) << 3);
  }
  // B: 2 glds rounds per matrix; rows n (64), row length H_DIM (k)
  const f16* gbase[2];
  const f16* ubase[2];
#pragma unroll
  for (int it = 0; it < 2; ++it) {
    int idx = tid + it * 256;
    int brow = idx >> 3, sl = idx & 7;
    size_t off = (size_t)(n0 + brow) * H_DIM + ((sl ^ (brow & 7)) << 3);
    gbase[it] = wg + off;
    ubase[it] = wu + off;
  }

  f32x4 accg[4][2], accu[4][2];
#pragma unroll
  for (int m = 0; m < 4; ++m)
#pragma unroll
    for (int n = 0; n < 2; ++n) { accg[m][n] = (f32x4)0.f; accu[m][n] = (f32x4)0.f; }

  const int NK = H_DIM / BK;                 // 16

#define G1_ISSUE(K0, BUF)                                                    \
  {                                                                          \
    f16* Ab = smem + (BUF) * 16384;                                          \
    f16* Bgb = Ab + 8192;                                                    \
    f16* Bub = Bgb + 4096;                                                   \
    sfence();                                                                \
    _Pragma("unroll")                                                        \
    for (int it = 0; it < 4; ++it)                                           \
      glds16(abase[it] + (K0), Ab + (tid + it * 256) * 8);                   \
    _Pragma("unroll")                                                        \
    for (int it = 0; it < 2; ++it) {                                         \
      glds16(gbase[it] + (K0), Bgb + (tid + it * 256) * 8);                  \
      glds16(ubase[it] + (K0), Bub + (tid + it * 256) * 8);                  \
    }                                                                        \
    sfence();                                                                \
  }

  G1_ISSUE(0, 0);
  for (int ks = 0; ks < NK; ++ks) {
    int buf = ks & 1;
    bar_vm0();                               // tile ks resident everywhere
    if (ks + 1 < NK) G1_ISSUE((ks + 1) * BK, buf ^ 1);
    const f16* Ab = smem + buf * 16384;
    const f16* Bgb = Ab + 8192;
    const f16* Bub = Bgb + 4096;
    __builtin_amdgcn_s_setprio(1);
#pragma unroll
    for (int kk = 0; kk < BK; kk += 32) {
      f16x8 a[4], bg[2], bu[2];
#pragma unroll
      for (int m = 0; m < 4; ++m) {
        int ar = wm * 64 + m * 16 + lr;
        a[m] = *(const f16x8*)(Ab + ar * BK + ((kk + lk) ^ ((ar & 7) << 3)));
      }
#pragma unroll
      for (int n = 0; n < 2; ++n) {
        int rowb = wn * 32 + n * 16 + lr;
        int ko = (kk + lk) ^ ((rowb & 7) << 3);
        bg[n] = *(const f16x8*)(Bgb + rowb * BK + ko);
        bu[n] = *(const f16x8*)(Bub + rowb * BK + ko);
      }
#pragma unroll
      for (int m = 0; m < 4; ++m)
#pragma unroll
        for (int n = 0; n < 2; ++n) {
          accg[m][n] = __builtin_amdgcn_mfma_f32_16x16x32_f16(a[m], bg[n], accg[m][n], 0, 0, 0);
          accu[m][n] = __builtin_amdgcn_mfma_f32_16x16x32_f16(a[m], bu[n], accu[m][n], 0, 0, 0);
        }
    }
    __builtin_amdgcn_s_setprio(0);
  }
#undef G1_ISSUE

  // epilogue: SwiGLU -> LDS bounce -> coalesced f16x8 stores
  __syncthreads();
#pragma unroll
  for (int m = 0; m < 4; ++m)
#pragma unroll
    for (int n = 0; n < 2; ++n)
#pragma unroll
      for (int j = 0; j < 4; ++j) {
        float g = accg[m][n][j], u = accu[m][n][j];
        float hv = g / (1.f + __expf(-g)) * u;
        Ct[wm * 64 + m * 16 + (lane >> 4) * 4 + j][wn * 32 + n * 16 + lr] = (f16)hv;
      }
  __syncthreads();
#pragma unroll
  for (int it = 0; it < 4; ++it) {
    int idx = tid + it * 256;
    int r = idx >> 3, g8 = (idx & 7) * 8;
    *(f16x8*)(hbuf + (size_t)(row0 + r) * I_DIM + n0 + g8) = *(const f16x8*)&Ct[r][g8];
  }
}

// ---------------------------------------------------------------- GEMM2 ---
// Same m97-X structure. B = dT[e][h][i] (rows n=H, cols k=I). BN=128.
__global__ __launch_bounds__(256, 2) void gemm2_kernel(
    const f16* __restrict__ hbuf,
    const f16* __restrict__ dT,
    const int* __restrict__ tile_expert, const int* __restrict__ tile_row0,
    const int* __restrict__ ntiles, f16* __restrict__ ybuf) {
  // grid 192*8 = 1536 = 8*192 consecutive per XCD
  int d = blockIdx.y * gridDim.x + blockIdx.x;
  int l = (d & 7) * 192 + (d >> 3);
  int bx = l % MAX_TILES;
  int n0 = (l / MAX_TILES) * 128;
  if (bx >= ntiles[0]) return;
  int e = tile_expert[bx];
  int row0 = tile_row0[bx];
  const f16* wd = dT + (size_t)e * WMAT;

  // LDS per buf: A 128*64 + Bd 128*64 = 16384 f16; dbuf = 64 KB
  __shared__ __align__(16) f16 smem[2 * 16384];
  f16 (*Ct)[136] = (f16(*)[136])smem;        // 17408 f16

  int tid = threadIdx.x;
  int lane = tid & 63, wid = tid >> 6;
  int wm = wid >> 1, wn = wid & 1;
  int lr = lane & 15, lk = (lane >> 4) * 8;

  const f16* abase[4];
  const f16* bbase[4];
#pragma unroll
  for (int it = 0; it < 4; ++it) {
    int idx = tid + it * 256;
    int arow = idx >> 3, sl = idx & 7;
    abase[it] = hbuf + (size_t)(row0 + arow) * I_DIM + ((sl ^ (arow & 7)) << 3);
    bbase[it] = wd + (size_t)(n0 + arow) * I_DIM + ((sl ^ (arow & 7)) << 3);
  }

  f32x4 acc[4][4];
#pragma unroll
  for (int m = 0; m < 4; ++m)
#pragma unroll
    for (int n = 0; n < 4; ++n) acc[m][n] = (f32x4)0.f;

  const int NK = I_DIM / BK;                 // 32

#define G2_ISSUE(K0, BUF)                                                    \
  {                                                                          \
    f16* Ab = smem + (BUF) * 16384;                                          \
    f16* Bb = Ab + 8192;                                                     \
    sfence();                                                                \
    _Pragma("unroll")                                                        \
    for (int it = 0; it < 4; ++it) {                                         \
      glds16(abase[it] + (K0), Ab + (tid + it * 256) * 8);                   \
      glds16(bbase[it] + (K0), Bb + (tid + it * 256) * 8);                   \
    }                                                                        \
    sfence();                                                                \
  }

  G2_ISSUE(0, 0);
  for (int ks = 0; ks < NK; ++ks) {
    int buf = ks & 1;
    bar_vm0();
    if (ks + 1 < NK) G2_ISSUE((ks + 1) * BK, buf ^ 1);
    const f16* Ab = smem + buf * 16384;
    const f16* Bb = Ab + 8192;
    __builtin_amdgcn_s_setprio(1);
#pragma unroll
    for (int kk = 0; kk < BK; kk += 32) {
      f16x8 a[4], bd[4];
#pragma unroll
      for (int m = 0; m < 4; ++m) {
        int ar = wm * 64 + m * 16 + lr;
        a[m] = *(const f16x8*)(Ab + ar * BK + ((kk + lk) ^ ((ar & 7) << 3)));
      }
#pragma unroll
      for (int n = 0; n < 4; ++n) {
        int rowb = wn * 64 + n * 16 + lr;
        bd[n] = *(const f16x8*)(Bb + rowb * BK + ((kk + lk) ^ ((rowb & 7) << 3)));
      }
#pragma unroll
      for (int m = 0; m < 4; ++m)
#pragma unroll
        for (int n = 0; n < 4; ++n)
          acc[m][n] = __builtin_amdgcn_mfma_f32_16x16x32_f16(a[m], bd[n], acc[m][n], 0, 0, 0);
    }
    __builtin_amdgcn_s_setprio(0);
  }
#undef G2_ISSUE

  __syncthreads();
#pragma unroll
  for (int m = 0; m < 4; ++m)
#pragma unroll
    for (int n = 0; n < 4; ++n)
#pragma unroll
      for (int j = 0; j < 4; ++j)
        Ct[wm * 64 + m * 16 + (lane >> 4) * 4 + j][wn * 64 + n * 16 + lr] =
            (f16)acc[m][n][j];
  __syncthreads();
#pragma unroll
  for (int it = 0; it < 8; ++it) {
    int idx = tid + it * 256;
    int r = idx >> 4, g8 = (idx & 15) * 8;
    *(f16x8*)(ybuf + (size_t)(row0 + r) * H_DIM + n0 + g8) = *(const f16x8*)&Ct[r][g8];
  }
}

// --------------------------------------------------------------- gather ---
__global__ void gather_kernel(const f16* __restrict__ ybuf,
                              const int* __restrict__ slot_of,
                              const float* __restrict__ weight_sel,
                              float* __restrict__ out) {
  int gid = blockIdx.x * blockDim.x + threadIdx.x;   // T*128
  int t = gid >> 7, s8 = (gid & 127) * 8;
  f16x8 ysh = *(const f16x8*)(ybuf + (size_t)t * H_DIM + s8);
  float a[8];
#pragma unroll
  for (int j = 0; j < 8; ++j) a[j] = (float)ysh[j];
#pragma unroll
  for (int k = 0; k < 4; ++k) {
    int sl = slot_of[t * 4 + k];
    float w = weight_sel[t * 4 + k];
    f16x8 v = *(const f16x8*)(ybuf + (size_t)sl * H_DIM + s8);
#pragma unroll
    for (int j = 0; j < 8; ++j) a[j] += w * (float)v[j];
  }
  float4 o0 = { a[0], a[1], a[2], a[3] };
  float4 o1 = { a[4], a[5], a[6], a[7] };
  *(float4*)(out + (size_t)t * H_DIM + s8) = o0;
  *(float4*)(out + (size_t)t * H_DIM + s8 + 4) = o1;
}

// ------------------------------------------------------------- launcher ---
extern "C" void kernel_launch(void* const* d_in, const int* in_sizes, int n_in,
                              void* d_out, int out_size, void* d_ws, size_t ws_size,
                              hipStream_t stream) {
  const float* x        = (const float*)d_in[0];
  const float* router_w = (const float*)d_in[1];
  const float* gate_w   = (const float*)d_in[2];
  const float* up_w     = (const float*)d_in[3];
  const float* down_w   = (const float*)d_in[4];
  const float* sgw      = (const float*)d_in[5];
  const float* suw      = (const float*)d_in[6];
  const float* sdw      = (const float*)d_in[7];
  float* out = (float*)d_out;

  char* w = (char*)d_ws;
  f16*   xb         = (f16*)w;   w += (size_t)T_TOK * H_DIM * 2;
  int*   expert_sel = (int*)w;   w += (size_t)TKTOT * 4;
  float* weight_sel = (float*)w; w += (size_t)TKTOT * 4;
  int*   slot_of    = (int*)w;   w += (size_t)TKTOT * 4;
  int*   counts     = (int*)w;   w += 256;
  int*   cursor     = (int*)w;   w += 256;
  int*   tile_exp   = (int*)w;   w += MAX_TILES * 4;
  int*   tile_row0  = (int*)w;   w += MAX_TILES * 4;
  int*   ntiles     = (int*)w;   w += 256;
  int*   row_token  = (int*)w;   w += (size_t)ROWS_MAX * 4;
  f16*   hbuf       = (f16*)w;   w += (size_t)ROWS_MAX * I_DIM * 2;
  f16*   ybuf       = (f16*)w;   w += (size_t)ROWS_MAX * H_DIM * 2;
  f16*   gT         = (f16*)w;   w += (size_t)(N_EXP + 1) * WMAT * 2;
  f16*   uT         = (f16*)w;   w += (size_t)(N_EXP + 1) * WMAT * 2;
  f16*   dT         = (f16*)w;   w += (size_t)(N_EXP + 1) * WMAT * 2;
  if ((size_t)(w - (char*)d_ws) > ws_size) return;  // ws too small: fail loud

  prep_kernel<<<(T_TOK * H_DIM / 4) / 256, 256, 0, stream>>>(x, xb, row_token, counts);
  // weight transpose+convert: gate/up [33][H][I] -> [33][I][H]; down [33][I][H]->[33][H][I]
  tcvt_kernel<<<(N_EXP + 1) * (H_DIM / 64) * (I_DIM / 64), 256, 0, stream>>>(
      gate_w, sgw, gT, H_DIM, I_DIM, I_DIM / 64);
  tcvt_kernel<<<(N_EXP + 1) * (H_DIM / 64) * (I_DIM / 64), 256, 0, stream>>>(
      up_w, suw, uT, H_DIM, I_DIM, I_DIM / 64);
  tcvt_kernel<<<(N_EXP + 1) * (I_DIM / 64) * (H_DIM / 64), 256, 0, stream>>>(
      down_w, sdw, dT, I_DIM, H_DIM, H_DIM / 64);
  router_kernel<<<T_TOK / 4, 256, 0, stream>>>(x, router_w, expert_sel, weight_sel, counts);
  scan_kernel<<<1, 64, 0, stream>>>(counts, cursor, tile_exp, tile_row0, ntiles);
  scatter_kernel<<<TKTOT / 256, 256, 0, stream>>>(expert_sel, cursor, row_token, slot_of);
  gemm1_kernel<<<dim3(MAX_TILES, I_DIM / 64), 256, 0, stream>>>(
      xb, gT, uT, row_token, tile_exp, tile_row0, ntiles, hbuf);
  gemm2_kernel<<<dim3(MAX_TILES, H_DIM / 128), 256, 0, stream>>>(
      hbuf, dT, tile_exp, tile_row0, ntiles, ybuf);
  gather_kernel<<<(T_TOK * (H_DIM / 8)) / 256, 256, 0, stream>>>(
      ybuf, slot_of, weight_sel, out);
}